// Round 15
// baseline (143.025 us; speedup 1.0000x reference)
//
#include <hip/hip_runtime.h>

// FANS: B=131072 rows x 16 states, MLP 12->64->64->1 with tanh, fp32 in/out.
// R15 = R14 with ONE change: grid decoupled from CHUNK. R14 post-mortem: dur
// pinned ~84us across VALU busy 46-75us / occ 31-41% / all frag placements ->
// latency-bound at 4 blocks/CU (grid demand, CHUNK=8 -> 1024 blocks). Unified
// regs ~76 (44 arch + ~32 accum) allow 6 waves/SIMD; LDS 17.4KB x6 fits.
// Fix: grid (96,16) = 1536 blocks = 6/CU, each block loops row-chunks
// ci = bx, bx+96, ... < 512 (5-6 chunks each, all resident, one generation).
// Single-variable experiment: if residency 6 -> predict 60-68us; if still 4,
// we've measured the real unified footprint (accums next).
// Kept from R14: pk-f16 tanh (v_pk_fma_f16 full-rate, trans pipe idle),
// hybrid frags (a0 LDS wave-0-staged / a1 32 regs), v_dot2 layer-3,
// zpl planes, Hd stride 36, per-wave LDS privacy, launch_bounds(256,4).

#define N_STATES 16
#define NCHUNKS  512          // 131072 rows / 256
#define GRIDX    96           // 96*16 = 1536 blocks = 6 per CU

typedef _Float16 f16x8 __attribute__((ext_vector_type(8)));
typedef float    f32x4 __attribute__((ext_vector_type(4)));
typedef __fp16   h2    __attribute__((ext_vector_type(2)));   // cvt_pkrtz type

__device__ __forceinline__ h2 pack2(float a, float b) {
    return __builtin_amdgcn_cvt_pkrtz(a, b);    // v_cvt_pkrtz_f16_f32
}
__device__ __forceinline__ unsigned int h2_bits(h2 v) {
    union { h2 h; unsigned int u; } x; x.h = v; return x.u;
}
__device__ __forceinline__ f16x8 u4_to_h8(uint4 v) {
    union { uint4 u; f16x8 h; } x; x.u = v; return x.h;
}
__device__ __forceinline__ uint4 h8_to_u4(f16x8 h) {
    union { f16x8 h; uint4 u; } x; x.h = h; return x.u;
}

// Packed-f16 tanh: xc = clamp(x, +-1.25); tanh ~ xc * P(xc^2), deg-4 P
// (Chebyshev interpolant, |err| <= 3e-5 in f32; f16 eval adds ~1e-3 — h is
// f16-rounded for the MFMA fragment anyway). All ops v_pk_* full-rate.
__device__ __forceinline__ h2 tanh_pk(h2 x) {
    const h2 hi = {(__fp16)1.25f, (__fp16)1.25f};
    const h2 lo = {(__fp16)-1.25f, (__fp16)-1.25f};
    x = __builtin_elementwise_min(__builtin_elementwise_max(x, lo), hi);
    h2 s = x * x;
    const h2 c4 = {(__fp16)0.00598591f, (__fp16)0.00598591f};
    const h2 c3 = {(__fp16)-0.03807894f, (__fp16)-0.03807894f};
    const h2 c2 = {(__fp16)0.12576901f, (__fp16)0.12576901f};
    const h2 c1 = {(__fp16)-0.33203310f, (__fp16)-0.33203310f};
    const h2 c0 = {(__fp16)0.99998110f, (__fp16)0.99998110f};
    h2 p = s * c4 + c3;     // v_pk_fma_f16 (fp-contract)
    p = s * p + c2;
    p = s * p + c1;
    p = s * p + c0;
    return x * p;
}

__global__ __launch_bounds__(256, 4) void fans_mfma_kernel(
    const float* __restrict__ x_f, const float* __restrict__ x_b,
    const float* __restrict__ u,   const float* __restrict__ W0,
    const float* __restrict__ W1,  const float* __restrict__ W2,
    float* __restrict__ out)
{
    __shared__ __align__(16) uint4 zplA[256];              // 4 KB: z dwords 0..3
    __shared__ __align__(16) uint2 zplB[256];              // 2 KB: u pair
    __shared__ __align__(16) unsigned int Hd[4][16][36];   // 9 KB, stride 144B
    __shared__ __align__(16) uint4 sA0[4][32];             // 2 KB: [t][q*16+c], q<2

    const int s   = blockIdx.y;
    const int tid = threadIdx.x;

    const int lid = tid & 63;
    const int w   = tid >> 6;     // wave id; wave w owns local rows [64w,64w+64)
    const int c   = lid & 15;
    const int q   = lid >> 4;

    // ---- wave 0 stages layer-1 fragments into LDS (identical across waves) ----
    if (tid < 64 && q < 2) {
        // A[m = feat 16t+c][k = 8q+j] = W0[s][feat][k], k<12 else 0
        const float* w0s = W0 + s * 768;
        #pragma unroll
        for (int t = 0; t < 4; ++t) {
            f16x8 v;
            #pragma unroll
            for (int j = 0; j < 8; ++j) {
                const int k = 8 * q + j;
                v[j] = (_Float16)((k < 12) ? w0s[(16 * t + c) * 12 + k] : 0.0f);
            }
            sA0[t][lid] = h8_to_u4(v);                  // lid = q*16+c < 32
        }
    }

    // ---- layer-2 fragments in registers (8 x f16x8 = 32 regs) ----
    // A[m = feat_out 16t+c][k = 32ks+8q+j] = W1[s][o][h]
    f16x8 a1[2][4];
    {
        const float* w1s = W1 + s * 4096;
        #pragma unroll
        for (int ks = 0; ks < 2; ++ks) {
            #pragma unroll
            for (int t = 0; t < 4; ++t) {
                const float4* p = (const float4*)(w1s + (16 * t + c) * 64 + 32 * ks + 8 * q);
                const float4 v0 = p[0], v1 = p[1];
                a1[ks][t] = (f16x8){(_Float16)v0.x, (_Float16)v0.y, (_Float16)v0.z, (_Float16)v0.w,
                                    (_Float16)v1.x, (_Float16)v1.y, (_Float16)v1.z, (_Float16)v1.w};
            }
        }
    }
    // W2 as packed f16 pairs: w2p[2t+u] = (w2[16t+4q+2u], w2[16t+4q+2u+1])
    h2 w2p[8];
    {
        const float* w2s = W2 + s * 64;
        #pragma unroll
        for (int t = 0; t < 4; ++t) {
            const int base = 16 * t + 4 * q;
            w2p[2 * t + 0] = pack2(w2s[base + 0], w2s[base + 1]);
            w2p[2 * t + 1] = pack2(w2s[base + 2], w2s[base + 3]);
        }
    }

    __syncthreads();   // one barrier per block: sA0 staging visible

    const int wrap = (s > 8) ? (s - 8) : 0;   // IDX[s] = {0..wrap-1}++{s..15}

    // ---- flexible chunk loop: 512 row-chunks strided over 96 x-blocks ----
    #pragma unroll 1
    for (int ci = blockIdx.x; ci < NCHUNKS; ci += GRIDX) {
        const int rbase = ci * 256;

        // ---- phase 1: gather z for own row, pack, write planes ----
        {
            const int row = rbase + tid;
            float zs[8];
            #pragma unroll
            for (int j = 0; j < 8; ++j) {
                const int idx = (j < wrap) ? j : (s + j - wrap);  // uniform
                zs[j] = (idx < 8) ? x_f[row * 8 + idx] : x_b[row * 8 + (idx - 8)];
            }
            const float4 uv = *(const float4*)(u + row * 4);
            zplA[tid] = make_uint4(h2_bits(pack2(zs[0], zs[1])), h2_bits(pack2(zs[2], zs[3])),
                                   h2_bits(pack2(zs[4], zs[5])), h2_bits(pack2(zs[6], zs[7])));
            zplB[tid] = make_uint2(h2_bits(pack2(uv.x, uv.y)), h2_bits(pack2(uv.z, uv.w)));
        }
        // No barrier: wave w reads only rows [64w,64w+64) which it wrote itself.

        // ---- phase 2: 4 M-tiles of 16 rows (own wave's rows only) ----
        #pragma unroll
        for (int m = 0; m < 4; ++m) {
            const int rowb = 64 * w + 16 * m;

            // z B-frag: B[k = 8q+j][n = row c]; k>=12 zero
            f16x8 zf = {0, 0, 0, 0, 0, 0, 0, 0};
            if (q == 0) {
                zf = u4_to_h8(zplA[rowb + c]);
            } else if (q == 1) {
                const uint2 b = zplB[rowb + c];
                zf = u4_to_h8(make_uint4(b.x, b.y, 0u, 0u));
            }

            // layer 1: C[row = feat 16t+4q+r][col = batch row c]
            f32x4 c1[4];
            #pragma unroll
            for (int t = 0; t < 4; ++t) {
                f16x8 a0t = {0, 0, 0, 0, 0, 0, 0, 0};
                if (q < 2) a0t = u4_to_h8(sA0[t][lid]);
                c1[t] = __builtin_amdgcn_mfma_f32_16x16x32_f16(
                    a0t, zf, (f32x4){0.f, 0.f, 0.f, 0.f}, 0, 0, 0);
            }

            // packed-f16 tanh -> LDS: dword P = 8t+2q holds feats (16t+4q, +1)
            #pragma unroll
            for (int t = 0; t < 4; ++t) {
                const h2 th0 = tanh_pk(pack2(c1[t][0], c1[t][1]));
                const h2 th1 = tanh_pk(pack2(c1[t][2], c1[t][3]));
                *(uint2*)&Hd[w][c][8 * t + 2 * q] = make_uint2(h2_bits(th0), h2_bits(th1));
            }

            // layer 2: B-frag[k = 32ks+8q+j][n = c] = Hd dwords 16ks+4q+0..3
            f32x4 c2[4] = {{0.f, 0.f, 0.f, 0.f}, {0.f, 0.f, 0.f, 0.f},
                           {0.f, 0.f, 0.f, 0.f}, {0.f, 0.f, 0.f, 0.f}};
            #pragma unroll
            for (int ks = 0; ks < 2; ++ks) {
                const f16x8 hb = u4_to_h8(*(const uint4*)&Hd[w][c][16 * ks + 4 * q]);
                #pragma unroll
                for (int t = 0; t < 4; ++t)
                    c2[t] = __builtin_amdgcn_mfma_f32_16x16x32_f16(a1[ks][t], hb, c2[t], 0, 0, 0);
            }

            // layer 3: packed tanh + v_dot2_f32_f16 accumulate (f32 accum)
            float ar0 = 0.f, ar1 = 0.f;
            #pragma unroll
            for (int t = 0; t < 4; ++t) {
                const h2 th0 = tanh_pk(pack2(c2[t][0], c2[t][1]));
                const h2 th1 = tanh_pk(pack2(c2[t][2], c2[t][3]));
                ar0 = __builtin_amdgcn_fdot2(th0, w2p[2 * t + 0], ar0, false);
                ar1 = __builtin_amdgcn_fdot2(th1, w2p[2 * t + 1], ar1, false);
            }
            float acc = ar0 + ar1;
            acc += __shfl_xor(acc, 16);
            acc += __shfl_xor(acc, 32);

            if (lid < 16)
                out[(rbase + rowb + lid) * N_STATES + s] = acc;
        }
    }
}

extern "C" void kernel_launch(void* const* d_in, const int* in_sizes, int n_in,
                              void* d_out, int out_size, void* d_ws, size_t ws_size,
                              hipStream_t stream) {
    const float* x_f = (const float*)d_in[0];
    const float* x_b = (const float*)d_in[1];
    const float* u   = (const float*)d_in[2];
    const float* W0  = (const float*)d_in[3];
    const float* W1  = (const float*)d_in[4];
    const float* W2  = (const float*)d_in[5];
    float* out = (float*)d_out;

    dim3 grid(GRIDX, N_STATES);                   // (96,16) = 1536 blocks = 6/CU
    fans_mfma_kernel<<<grid, 256, 0, stream>>>(x_f, x_b, u, W0, W1, W2, out);
}

// Round 16
// 136.787 us; speedup vs baseline: 1.0456x; 1.0456x over previous
//
#include <hip/hip_runtime.h>

// FANS: B=131072 rows x 16 states, MLP 12->64->64->1 with tanh, fp32 in/out.
// R16: manual 2-wide tile pipeline. R15 closed the occupancy theory: plateau
// ~84-88us is invariant across occ 31-41%, VALU 46-75us, frag placement,
// grid shape. Per-pipe accounting: dur ~= SUM of pipe busies (VALU 46 + LDS
// ~28 + trans ~8 + MFMA 11) -> pipes run serially: one dependency chain per
// wave, waves in phase. Structural cause: the unrolled m-loop reuses ONE Hd
// region per wave -> LDS WAR hazard the compiler can't rename -> no cross-
// tile ILP. Fix: process tiles in PAIRS with separate Hd buffers
// (Hd[w][2][16][36], +9KB) and explicitly interleaved phases; sA0 read once
// per pair. LDS 26.6KB (6 blocks/CU possible); peak regs ~110 < 128 cap.
// Kept from R14 (best, 84.7us): pk-f16 tanh, a0 LDS / a1 regs, v_dot2
// layer-3, CHUNK=8 blocked chunks, launch_bounds(256,4).

#define N_STATES 16
#define CHUNK    8

typedef _Float16 f16x8 __attribute__((ext_vector_type(8)));
typedef float    f32x4 __attribute__((ext_vector_type(4)));
typedef __fp16   h2    __attribute__((ext_vector_type(2)));   // cvt_pkrtz type

__device__ __forceinline__ h2 pack2(float a, float b) {
    return __builtin_amdgcn_cvt_pkrtz(a, b);    // v_cvt_pkrtz_f16_f32
}
__device__ __forceinline__ unsigned int h2_bits(h2 v) {
    union { h2 h; unsigned int u; } x; x.h = v; return x.u;
}
__device__ __forceinline__ f16x8 u4_to_h8(uint4 v) {
    union { uint4 u; f16x8 h; } x; x.u = v; return x.h;
}
__device__ __forceinline__ uint4 h8_to_u4(f16x8 h) {
    union { f16x8 h; uint4 u; } x; x.h = h; return x.u;
}

// Packed-f16 tanh: clamp(+-1.25) then odd deg-9 Chebyshev poly; v_pk_* full-rate.
__device__ __forceinline__ h2 tanh_pk(h2 x) {
    const h2 hi = {(__fp16)1.25f, (__fp16)1.25f};
    const h2 lo = {(__fp16)-1.25f, (__fp16)-1.25f};
    x = __builtin_elementwise_min(__builtin_elementwise_max(x, lo), hi);
    h2 s = x * x;
    const h2 c4 = {(__fp16)0.00598591f, (__fp16)0.00598591f};
    const h2 c3 = {(__fp16)-0.03807894f, (__fp16)-0.03807894f};
    const h2 c2 = {(__fp16)0.12576901f, (__fp16)0.12576901f};
    const h2 c1 = {(__fp16)-0.33203310f, (__fp16)-0.33203310f};
    const h2 c0 = {(__fp16)0.99998110f, (__fp16)0.99998110f};
    h2 p = s * c4 + c3;
    p = s * p + c2;
    p = s * p + c1;
    p = s * p + c0;
    return x * p;
}

__global__ __launch_bounds__(256, 4) void fans_mfma_kernel(
    const float* __restrict__ x_f, const float* __restrict__ x_b,
    const float* __restrict__ u,   const float* __restrict__ W0,
    const float* __restrict__ W1,  const float* __restrict__ W2,
    float* __restrict__ out)
{
    __shared__ __align__(16) uint4 zplA[256];                 // 4 KB
    __shared__ __align__(16) uint2 zplB[256];                 // 2 KB
    __shared__ __align__(16) unsigned int Hd[4][2][16][36];   // 18 KB (A/B bufs)
    __shared__ __align__(16) uint4 sA0[4][32];                // 2 KB

    const int s   = blockIdx.y;
    const int tid = threadIdx.x;
    const int b0  = blockIdx.x * (256 * CHUNK);

    const int lid = tid & 63;
    const int w   = tid >> 6;
    const int c   = lid & 15;
    const int q   = lid >> 4;

    // ---- wave 0 stages layer-1 fragments into LDS ----
    if (tid < 64 && q < 2) {
        const float* w0s = W0 + s * 768;
        #pragma unroll
        for (int t = 0; t < 4; ++t) {
            f16x8 v;
            #pragma unroll
            for (int j = 0; j < 8; ++j) {
                const int k = 8 * q + j;
                v[j] = (_Float16)((k < 12) ? w0s[(16 * t + c) * 12 + k] : 0.0f);
            }
            sA0[t][lid] = h8_to_u4(v);
        }
    }

    // ---- layer-2 fragments in registers (32 VGPRs) ----
    f16x8 a1[2][4];
    {
        const float* w1s = W1 + s * 4096;
        #pragma unroll
        for (int ks = 0; ks < 2; ++ks) {
            #pragma unroll
            for (int t = 0; t < 4; ++t) {
                const float4* p = (const float4*)(w1s + (16 * t + c) * 64 + 32 * ks + 8 * q);
                const float4 v0 = p[0], v1 = p[1];
                a1[ks][t] = (f16x8){(_Float16)v0.x, (_Float16)v0.y, (_Float16)v0.z, (_Float16)v0.w,
                                    (_Float16)v1.x, (_Float16)v1.y, (_Float16)v1.z, (_Float16)v1.w};
            }
        }
    }
    // W2 as packed f16 pairs
    h2 w2p[8];
    {
        const float* w2s = W2 + s * 64;
        #pragma unroll
        for (int t = 0; t < 4; ++t) {
            const int base = 16 * t + 4 * q;
            w2p[2 * t + 0] = pack2(w2s[base + 0], w2s[base + 1]);
            w2p[2 * t + 1] = pack2(w2s[base + 2], w2s[base + 3]);
        }
    }

    __syncthreads();

    const int wrap = (s > 8) ? (s - 8) : 0;

    #pragma unroll 1
    for (int ch = 0; ch < CHUNK; ++ch) {
        const int rbase = b0 + ch * 256;

        // ---- phase 1: gather z for own row, pack, write planes ----
        {
            const int row = rbase + tid;
            float zs[8];
            #pragma unroll
            for (int j = 0; j < 8; ++j) {
                const int idx = (j < wrap) ? j : (s + j - wrap);
                zs[j] = (idx < 8) ? x_f[row * 8 + idx] : x_b[row * 8 + (idx - 8)];
            }
            const float4 uv = *(const float4*)(u + row * 4);
            zplA[tid] = make_uint4(h2_bits(pack2(zs[0], zs[1])), h2_bits(pack2(zs[2], zs[3])),
                                   h2_bits(pack2(zs[4], zs[5])), h2_bits(pack2(zs[6], zs[7])));
            zplB[tid] = make_uint2(h2_bits(pack2(uv.x, uv.y)), h2_bits(pack2(uv.z, uv.w)));
        }
        // No barrier: wave w reads only rows [64w,64w+64) which it wrote itself.

        // ---- phase 2: 2 pairs of 16-row tiles, explicitly interleaved ----
        #pragma unroll
        for (int mp = 0; mp < 2; ++mp) {
            const int rowA = 64 * w + 32 * mp;      // tile A = 2mp
            const int rowB = rowA + 16;             // tile B = 2mp+1

            // z B-frags for both tiles (independent LDS reads)
            f16x8 zfA = {0, 0, 0, 0, 0, 0, 0, 0};
            f16x8 zfB = {0, 0, 0, 0, 0, 0, 0, 0};
            if (q == 0) {
                zfA = u4_to_h8(zplA[rowA + c]);
                zfB = u4_to_h8(zplA[rowB + c]);
            } else if (q == 1) {
                const uint2 bA = zplB[rowA + c];
                const uint2 bB = zplB[rowB + c];
                zfA = u4_to_h8(make_uint4(bA.x, bA.y, 0u, 0u));
                zfB = u4_to_h8(make_uint4(bB.x, bB.y, 0u, 0u));
            }

            // layer 1: 8 independent MFMAs (a0 frag read once, shared by A/B)
            f32x4 c1A[4], c1B[4];
            #pragma unroll
            for (int t = 0; t < 4; ++t) {
                f16x8 a0t = {0, 0, 0, 0, 0, 0, 0, 0};
                if (q < 2) a0t = u4_to_h8(sA0[t][lid]);
                c1A[t] = __builtin_amdgcn_mfma_f32_16x16x32_f16(
                    a0t, zfA, (f32x4){0.f, 0.f, 0.f, 0.f}, 0, 0, 0);
                c1B[t] = __builtin_amdgcn_mfma_f32_16x16x32_f16(
                    a0t, zfB, (f32x4){0.f, 0.f, 0.f, 0.f}, 0, 0, 0);
            }

            // tanh -> pack -> DISJOINT Hd buffers (no WAR between A and B)
            #pragma unroll
            for (int t = 0; t < 4; ++t) {
                const h2 a0p = tanh_pk(pack2(c1A[t][0], c1A[t][1]));
                const h2 a1p = tanh_pk(pack2(c1A[t][2], c1A[t][3]));
                const h2 b0p = tanh_pk(pack2(c1B[t][0], c1B[t][1]));
                const h2 b1p = tanh_pk(pack2(c1B[t][2], c1B[t][3]));
                *(uint2*)&Hd[w][0][c][8 * t + 2 * q] = make_uint2(h2_bits(a0p), h2_bits(a1p));
                *(uint2*)&Hd[w][1][c][8 * t + 2 * q] = make_uint2(h2_bits(b0p), h2_bits(b1p));
            }

            // layer 2: 16 MFMAs, A/B independent
            f32x4 c2A[4] = {{0.f,0.f,0.f,0.f},{0.f,0.f,0.f,0.f},{0.f,0.f,0.f,0.f},{0.f,0.f,0.f,0.f}};
            f32x4 c2B[4] = {{0.f,0.f,0.f,0.f},{0.f,0.f,0.f,0.f},{0.f,0.f,0.f,0.f},{0.f,0.f,0.f,0.f}};
            #pragma unroll
            for (int ks = 0; ks < 2; ++ks) {
                const f16x8 hbA = u4_to_h8(*(const uint4*)&Hd[w][0][c][16 * ks + 4 * q]);
                const f16x8 hbB = u4_to_h8(*(const uint4*)&Hd[w][1][c][16 * ks + 4 * q]);
                #pragma unroll
                for (int t = 0; t < 4; ++t) {
                    c2A[t] = __builtin_amdgcn_mfma_f32_16x16x32_f16(a1[ks][t], hbA, c2A[t], 0, 0, 0);
                    c2B[t] = __builtin_amdgcn_mfma_f32_16x16x32_f16(a1[ks][t], hbB, c2B[t], 0, 0, 0);
                }
            }

            // layer 3: packed tanh + v_dot2, both tiles
            float arA0 = 0.f, arA1 = 0.f, arB0 = 0.f, arB1 = 0.f;
            #pragma unroll
            for (int t = 0; t < 4; ++t) {
                arA0 = __builtin_amdgcn_fdot2(tanh_pk(pack2(c2A[t][0], c2A[t][1])), w2p[2*t+0], arA0, false);
                arA1 = __builtin_amdgcn_fdot2(tanh_pk(pack2(c2A[t][2], c2A[t][3])), w2p[2*t+1], arA1, false);
                arB0 = __builtin_amdgcn_fdot2(tanh_pk(pack2(c2B[t][0], c2B[t][1])), w2p[2*t+0], arB0, false);
                arB1 = __builtin_amdgcn_fdot2(tanh_pk(pack2(c2B[t][2], c2B[t][3])), w2p[2*t+1], arB1, false);
            }
            float accA = arA0 + arA1;
            float accB = arB0 + arB1;
            accA += __shfl_xor(accA, 16);
            accA += __shfl_xor(accA, 32);
            accB += __shfl_xor(accB, 16);
            accB += __shfl_xor(accB, 32);

            if (lid < 16) {
                out[(rbase + rowA + lid) * N_STATES + s] = accA;
                out[(rbase + rowB + lid) * N_STATES + s] = accB;
            }
        }
    }
}

extern "C" void kernel_launch(void* const* d_in, const int* in_sizes, int n_in,
                              void* d_out, int out_size, void* d_ws, size_t ws_size,
                              hipStream_t stream) {
    const float* x_f = (const float*)d_in[0];
    const float* x_b = (const float*)d_in[1];
    const float* u   = (const float*)d_in[2];
    const float* W0  = (const float*)d_in[3];
    const float* W1  = (const float*)d_in[4];
    const float* W2  = (const float*)d_in[5];
    float* out = (float*)d_out;

    const int nb = in_sizes[0] / 8;                 // 131072 = 64 * 2048
    dim3 grid(nb / (256 * CHUNK), N_STATES);        // (64, 16) = 1024 blocks
    fans_mfma_kernel<<<grid, 256, 0, stream>>>(x_f, x_b, u, W0, W1, W2, out);
}

// Round 17
// 128.229 us; speedup vs baseline: 1.1154x; 1.0667x over previous
//
#include <hip/hip_runtime.h>

// FANS: B=131072 rows x 16 states, MLP 12->64->64->1 with tanh, fp32 in/out.
// R17: 32x32x16 MFMA for both layers. R16 (2-wide 16x16 pipeline) gave only
// +4%: measured ~1k cyc/pair of chain stall that 4 waves can't fill, and
// widening needs accums that cap occupancy (catch-22, now quantified).
// 32x32 tiles attack it: N=32 rows/tile = R16's pair in ONE tile with HALF
// the accumulator regs (16 f32/lane per layer vs 32); a0 = 8 regs (sA0 LDS
// eliminated); tail = 1 shfl + 1 store (vs 4+2); 2+8 MFMAs per 32 rows
// (vs 4+16). Layouts: C col=lane&31, row=(r&3)+8(r>>2)+4(lane>>5) [verified];
// A[m=lane&31][k=8(lane>>5)+j], B[k=8(lane>>5)+j][n=lane&31] (mirror of the
// verified 16x16x32 convention). H stored pair-packed by feature-pair index:
// write b64s at p=16Mh+4a+2h, layer-2 B-frag = one b128 at p=8kc+4h.
// Kept: pk-f16 tanh, a1 in 32 regs, v_dot2 layer-3, zpl planes, CHUNK=8,
// launch_bounds(256,4). Tripwires: absmax>=1e-2 -> layout wrong; FETCH>>10MB
// -> spill.

#define N_STATES 16
#define CHUNK    8

typedef _Float16 f16x8  __attribute__((ext_vector_type(8)));
typedef float    f32x16 __attribute__((ext_vector_type(16)));
typedef __fp16   h2     __attribute__((ext_vector_type(2)));

__device__ __forceinline__ h2 pack2(float a, float b) {
    return __builtin_amdgcn_cvt_pkrtz(a, b);
}
__device__ __forceinline__ unsigned int h2_bits(h2 v) {
    union { h2 h; unsigned int u; } x; x.h = v; return x.u;
}
__device__ __forceinline__ f16x8 u4_to_h8(uint4 v) {
    union { uint4 u; f16x8 h; } x; x.u = v; return x.h;
}

// Packed-f16 tanh: clamp(+-1.25) then odd Chebyshev poly; v_pk_* full-rate.
__device__ __forceinline__ h2 tanh_pk(h2 x) {
    const h2 hi = {(__fp16)1.25f, (__fp16)1.25f};
    const h2 lo = {(__fp16)-1.25f, (__fp16)-1.25f};
    x = __builtin_elementwise_min(__builtin_elementwise_max(x, lo), hi);
    h2 s = x * x;
    const h2 c4 = {(__fp16)0.00598591f, (__fp16)0.00598591f};
    const h2 c3 = {(__fp16)-0.03807894f, (__fp16)-0.03807894f};
    const h2 c2 = {(__fp16)0.12576901f, (__fp16)0.12576901f};
    const h2 c1 = {(__fp16)-0.33203310f, (__fp16)-0.33203310f};
    const h2 c0 = {(__fp16)0.99998110f, (__fp16)0.99998110f};
    h2 p = s * c4 + c3;
    p = s * p + c2;
    p = s * p + c1;
    p = s * p + c0;
    return x * p;
}

__global__ __launch_bounds__(256, 4) void fans_mfma_kernel(
    const float* __restrict__ x_f, const float* __restrict__ x_b,
    const float* __restrict__ u,   const float* __restrict__ W0,
    const float* __restrict__ W1,  const float* __restrict__ W2,
    float* __restrict__ out)
{
    __shared__ __align__(16) uint4 zplA[256];              // 4 KB: z dwords 0..3
    __shared__ __align__(16) uint2 zplB[256];              // 2 KB: u pair
    __shared__ __align__(16) unsigned int Hd[4][32][36];   // 18 KB: [wave][row][pair]

    const int s   = blockIdx.y;
    const int tid = threadIdx.x;
    const int b0  = blockIdx.x * (256 * CHUNK);

    const int lid = tid & 63;
    const int w   = tid >> 6;     // wave id; wave w owns local rows [64w,64w+64)
    const int n   = lid & 31;     // batch row within 32-tile / feat row for A
    const int h   = lid >> 5;     // K-half (k = 8h+j)

    // ---- layer-1 A-frags in regs (2 x f16x8 = 8 regs) ----
    // a0[Mh][j] = W0[s][feat=32Mh+n][k=8h+j], k<12 else 0
    f16x8 a0[2];
    {
        const float* w0s = W0 + s * 768;
        #pragma unroll
        for (int Mh = 0; Mh < 2; ++Mh) {
            const float* base = w0s + (32 * Mh + n) * 12;
            f16x8 v;
            if (h == 0) {
                const float4 v0 = *(const float4*)(base + 0);
                const float4 v1 = *(const float4*)(base + 4);
                v = (f16x8){(_Float16)v0.x, (_Float16)v0.y, (_Float16)v0.z, (_Float16)v0.w,
                            (_Float16)v1.x, (_Float16)v1.y, (_Float16)v1.z, (_Float16)v1.w};
            } else {
                const float4 v0 = *(const float4*)(base + 8);   // k=8..11
                v = (f16x8){(_Float16)v0.x, (_Float16)v0.y, (_Float16)v0.z, (_Float16)v0.w,
                            (_Float16)0.f, (_Float16)0.f, (_Float16)0.f, (_Float16)0.f};
            }
            a0[Mh] = v;
        }
    }
    // ---- layer-2 A-frags in regs (8 x f16x8 = 32 regs) ----
    // a1[Mh][kc][j] = W1[s][feat_out=32Mh+n][k=16kc+8h+j]
    f16x8 a1[2][4];
    {
        const float* w1s = W1 + s * 4096;
        #pragma unroll
        for (int Mh = 0; Mh < 2; ++Mh) {
            #pragma unroll
            for (int kc = 0; kc < 4; ++kc) {
                const float4* p = (const float4*)(w1s + (32 * Mh + n) * 64 + 16 * kc + 8 * h);
                const float4 v0 = p[0], v1 = p[1];
                a1[Mh][kc] = (f16x8){(_Float16)v0.x, (_Float16)v0.y, (_Float16)v0.z, (_Float16)v0.w,
                                     (_Float16)v1.x, (_Float16)v1.y, (_Float16)v1.z, (_Float16)v1.w};
            }
        }
    }
    // ---- W2 packed pairs: this lane's feats = 32Mh + 8a + 2b + 4h ----
    h2 w2p[16];
    {
        const float* w2s = W2 + s * 64;
        #pragma unroll
        for (int Mh = 0; Mh < 2; ++Mh)
            #pragma unroll
            for (int k = 0; k < 8; ++k) {
                const int f = 32 * Mh + 8 * (k >> 1) + 2 * (k & 1) + 4 * h;
                w2p[8 * Mh + k] = pack2(w2s[f], w2s[f + 1]);
            }
    }

    const int wrap = (s > 8) ? (s - 8) : 0;   // IDX[s] = {0..wrap-1}++{s..15}

    #pragma unroll 1
    for (int ch = 0; ch < CHUNK; ++ch) {
        const int rbase = b0 + ch * 256;

        // ---- phase 1: gather z for own row, pack, write planes ----
        {
            const int row = rbase + tid;
            float zs[8];
            #pragma unroll
            for (int j = 0; j < 8; ++j) {
                const int idx = (j < wrap) ? j : (s + j - wrap);  // uniform
                zs[j] = (idx < 8) ? x_f[row * 8 + idx] : x_b[row * 8 + (idx - 8)];
            }
            const float4 uv = *(const float4*)(u + row * 4);
            zplA[tid] = make_uint4(h2_bits(pack2(zs[0], zs[1])), h2_bits(pack2(zs[2], zs[3])),
                                   h2_bits(pack2(zs[4], zs[5])), h2_bits(pack2(zs[6], zs[7])));
            zplB[tid] = make_uint2(h2_bits(pack2(uv.x, uv.y)), h2_bits(pack2(uv.z, uv.w)));
        }
        // No barrier: wave w reads only rows [64w,64w+64) it wrote itself;
        // Hd row n is written/read by lanes (n,0)/(n,1) of the same wave.

        // ---- phase 2: two 32-row tiles ----
        #pragma unroll
        for (int m = 0; m < 2; ++m) {
            const int rowb = 64 * w + 32 * m;

            // z B-frag: B[k=8h+j][n]: h=0 -> z dwords 0..3; h=1 -> u pair + 0
            f16x8 zf;
            if (h == 0) {
                zf = u4_to_h8(zplA[rowb + n]);
            } else {
                const uint2 b = zplB[rowb + n];
                zf = u4_to_h8(make_uint4(b.x, b.y, 0u, 0u));
            }

            // layer 1: 2 MFMAs (M-halves), C1[Mh][r] = feat 32Mh+(r&3)+8(r>>2)+4h, col n
            const f32x16 z16 = {0.f,0.f,0.f,0.f,0.f,0.f,0.f,0.f,
                                0.f,0.f,0.f,0.f,0.f,0.f,0.f,0.f};
            f32x16 c1a = __builtin_amdgcn_mfma_f32_32x32x16_f16(a0[0], zf, z16, 0, 0, 0);
            f32x16 c1b = __builtin_amdgcn_mfma_f32_32x32x16_f16(a0[1], zf, z16, 0, 0, 0);

            // tanh -> pair-pack -> Hd[w][n][pair]: pairs p=16Mh+4a+2h, +1
            #pragma unroll
            for (int a = 0; a < 4; ++a) {
                const int r = 4 * a;
                *(uint2*)&Hd[w][n][16 * 0 + 4 * a + 2 * h] =
                    make_uint2(h2_bits(tanh_pk(pack2(c1a[r], c1a[r + 1]))),
                               h2_bits(tanh_pk(pack2(c1a[r + 2], c1a[r + 3]))));
                *(uint2*)&Hd[w][n][16 * 1 + 4 * a + 2 * h] =
                    make_uint2(h2_bits(tanh_pk(pack2(c1b[r], c1b[r + 1]))),
                               h2_bits(tanh_pk(pack2(c1b[r + 2], c1b[r + 3]))));
            }

            // layer 2: B-frag chain kc: features 16kc+8h+j = pairs 8kc+4h+[0..4) (b128)
            f32x16 c2a = z16, c2b = z16;
            #pragma unroll
            for (int kc = 0; kc < 4; ++kc) {
                const f16x8 hb = u4_to_h8(*(const uint4*)&Hd[w][n][8 * kc + 4 * h]);
                c2a = __builtin_amdgcn_mfma_f32_32x32x16_f16(a1[0][kc], hb, c2a, 0, 0, 0);
                c2b = __builtin_amdgcn_mfma_f32_32x32x16_f16(a1[1][kc], hb, c2b, 0, 0, 0);
            }

            // layer 3: packed tanh + v_dot2; this lane covers 32 feats of row n
            float ar0 = 0.f, ar1 = 0.f;
            #pragma unroll
            for (int a = 0; a < 4; ++a) {
                const int r = 4 * a;
                ar0 = __builtin_amdgcn_fdot2(tanh_pk(pack2(c2a[r], c2a[r + 1])), w2p[2 * a + 0], ar0, false);
                ar0 = __builtin_amdgcn_fdot2(tanh_pk(pack2(c2a[r + 2], c2a[r + 3])), w2p[2 * a + 1], ar0, false);
                ar1 = __builtin_amdgcn_fdot2(tanh_pk(pack2(c2b[r], c2b[r + 1])), w2p[8 + 2 * a + 0], ar1, false);
                ar1 = __builtin_amdgcn_fdot2(tanh_pk(pack2(c2b[r + 2], c2b[r + 3])), w2p[8 + 2 * a + 1], ar1, false);
            }
            float acc = ar0 + ar1;
            acc += __shfl_xor(acc, 32);       // combine h=0/h=1 halves

            if (lid < 32)
                out[(rbase + rowb + n) * N_STATES + s] = acc;
        }
    }
}

extern "C" void kernel_launch(void* const* d_in, const int* in_sizes, int n_in,
                              void* d_out, int out_size, void* d_ws, size_t ws_size,
                              hipStream_t stream) {
    const float* x_f = (const float*)d_in[0];
    const float* x_b = (const float*)d_in[1];
    const float* u   = (const float*)d_in[2];
    const float* W0  = (const float*)d_in[3];
    const float* W1  = (const float*)d_in[4];
    const float* W2  = (const float*)d_in[5];
    float* out = (float*)d_out;

    const int nb = in_sizes[0] / 8;                 // 131072 = 64 * 2048
    dim3 grid(nb / (256 * CHUNK), N_STATES);        // (64, 16) = 1024 blocks
    fans_mfma_kernel<<<grid, 256, 0, stream>>>(x_f, x_b, u, W0, W1, W2, out);
}